// Round 2
// baseline (441.907 us; speedup 1.0000x reference)
//
#include <hip/hip_runtime.h>
#include <stdint.h>

// One wave (64 threads) per (b,h) row. C=4, H=W=1024 fixed. All float32.
// x layout  : [B,C,H,W]  -> x[((b*4+c)*1024 + h)*1024 + w]
// out layout: [B,H,C,W]  -> out[((b*1024+h)*4 + c)*1024 + w]
//
// Algebra (exact): with S[i] = sum_w x_i(w), G[i][j] = sum_w x_i(w)x_j(w):
//   scores[c][d] = scale*( wq[c]·G·wk[d] + bq[c]*(wk[d]·S) + bk[d]*(wq[c]·S) + W*bq[c]*bk[d] )
//   out[c][w]    = sum_i (attn[c]·wv[:,i]) * x_i(w) + attn[c]·bv
// => x is read ONCE (held in VGPRs), out written once. 512 MB total HBM traffic.
__global__ __launch_bounds__(64, 4)
void fused_attn_c4_f32(const float* __restrict__ x,
                       const float* __restrict__ wq, const float* __restrict__ bq,
                       const float* __restrict__ wk, const float* __restrict__ bk,
                       const float* __restrict__ wv, const float* __restrict__ bv,
                       float* __restrict__ out)
{
    constexpr int Hc = 1024, Wc = 1024;
    const int t   = threadIdx.x;          // 0..63
    const int blk = blockIdx.x;           // b*1024 + h
    const int b   = blk >> 10;
    const int h   = blk & 1023;

    // ---- load raw x: 4 channels x 4 quarters x float4 -- fully coalesced
    // lane t covers w in { q*256 + 4t .. q*256 + 4t+3 }, q = 0..3
    float4 raw[4][4];
#pragma unroll
    for (int c = 0; c < 4; ++c) {
        const float* p = x + ((size_t)(b * 4 + c) * Hc + h) * Wc + t * 4;
#pragma unroll
        for (int q = 0; q < 4; ++q)
            raw[c][q] = *reinterpret_cast<const float4*>(p + q * 256);
    }

    // ---- per-thread accumulate S[4] (acc 0..3) and Gram lower-tri (acc 4..13)
    float acc[14];
#pragma unroll
    for (int i = 0; i < 14; ++i) acc[i] = 0.f;

#pragma unroll
    for (int q = 0; q < 4; ++q) {
#pragma unroll
        for (int j = 0; j < 4; ++j) {
            float x0 = (&raw[0][q].x)[j];
            float x1 = (&raw[1][q].x)[j];
            float x2 = (&raw[2][q].x)[j];
            float x3 = (&raw[3][q].x)[j];
            acc[0] += x0; acc[1] += x1; acc[2] += x2; acc[3] += x3;
            acc[4]  += x0 * x0;
            acc[5]  += x1 * x0;  acc[6]  += x1 * x1;
            acc[7]  += x2 * x0;  acc[8]  += x2 * x1;  acc[9]  += x2 * x2;
            acc[10] += x3 * x0;  acc[11] += x3 * x1;  acc[12] += x3 * x2;  acc[13] += x3 * x3;
        }
    }

    // ---- 64-lane butterfly reduction (single wave per block => no LDS/barrier)
#pragma unroll
    for (int i = 0; i < 14; ++i) {
        float v = acc[i];
#pragma unroll
        for (int off = 32; off > 0; off >>= 1) v += __shfl_xor(v, off, 64);
        acc[i] = v;
    }

    float S[4] = { acc[0], acc[1], acc[2], acc[3] };
    float G[4][4];
    G[0][0] = acc[4];
    G[1][0] = G[0][1] = acc[5];  G[1][1] = acc[6];
    G[2][0] = G[0][2] = acc[7];  G[2][1] = G[1][2] = acc[8];  G[2][2] = acc[9];
    G[3][0] = G[0][3] = acc[10]; G[3][1] = G[1][3] = acc[11]; G[3][2] = G[2][3] = acc[12];
    G[3][3] = acc[13];

    // ---- tiny weights (uniform per block; L1/L2-resident scalarizable loads)
    float fwq[4][4], fwk[4][4], fwv[4][4], fbq[4], fbk[4], fbv[4];
#pragma unroll
    for (int i = 0; i < 4; ++i) {
#pragma unroll
        for (int j = 0; j < 4; ++j) {
            fwq[i][j] = wq[i * 4 + j];
            fwk[i][j] = wk[i * 4 + j];
            fwv[i][j] = wv[i * 4 + j];
        }
        fbq[i] = bq[i];
        fbk[i] = bk[i];
        fbv[i] = bv[i];
    }

    // ---- scores via Gram identity, softmax, effective V-projection
    const float scale = 0.03125f;     // 1/sqrt(1024)
    const float Wf = 1024.f;

    float qS[4], kS[4], A[4][4];
#pragma unroll
    for (int c = 0; c < 4; ++c) {
        qS[c] = fwq[c][0]*S[0] + fwq[c][1]*S[1] + fwq[c][2]*S[2] + fwq[c][3]*S[3];
        kS[c] = fwk[c][0]*S[0] + fwk[c][1]*S[1] + fwk[c][2]*S[2] + fwk[c][3]*S[3];
#pragma unroll
        for (int j = 0; j < 4; ++j)
            A[c][j] = fwq[c][0]*G[0][j] + fwq[c][1]*G[1][j] + fwq[c][2]*G[2][j] + fwq[c][3]*G[3][j];
    }

    float weff[4][4], beff[4];
#pragma unroll
    for (int c = 0; c < 4; ++c) {
        float s[4];
#pragma unroll
        for (int d = 0; d < 4; ++d) {
            s[d] = scale * (A[c][0]*fwk[d][0] + A[c][1]*fwk[d][1] +
                            A[c][2]*fwk[d][2] + A[c][3]*fwk[d][3]
                            + fbq[c]*kS[d] + fbk[d]*qS[c] + Wf*fbq[c]*fbk[d]);
        }
        float m  = fmaxf(fmaxf(s[0], s[1]), fmaxf(s[2], s[3]));
        float e0 = __expf(s[0]-m), e1 = __expf(s[1]-m), e2 = __expf(s[2]-m), e3 = __expf(s[3]-m);
        float inv = 1.f / (e0 + e1 + e2 + e3);
        float a0 = e0*inv, a1 = e1*inv, a2 = e2*inv, a3 = e3*inv;
#pragma unroll
        for (int i = 0; i < 4; ++i)
            weff[c][i] = a0*fwv[0][i] + a1*fwv[1][i] + a2*fwv[2][i] + a3*fwv[3][i];
        beff[c] = a0*fbv[0] + a1*fbv[1] + a2*fbv[2] + a3*fbv[3];
    }

    // ---- epilogue: out[c][w] = beff[c] + sum_i weff[c][i] * x_i(w)
#pragma unroll
    for (int c = 0; c < 4; ++c) {
        float* po = out + ((size_t)blk * 4 + c) * Wc + t * 4;
#pragma unroll
        for (int q = 0; q < 4; ++q) {
            float4 o;
#pragma unroll
            for (int j = 0; j < 4; ++j) {
                (&o.x)[j] = beff[c]
                          + weff[c][0] * (&raw[0][q].x)[j]
                          + weff[c][1] * (&raw[1][q].x)[j]
                          + weff[c][2] * (&raw[2][q].x)[j]
                          + weff[c][3] * (&raw[3][q].x)[j];
            }
            *reinterpret_cast<float4*>(po + q * 256) = o;
        }
    }
}

extern "C" void kernel_launch(void* const* d_in, const int* in_sizes, int n_in,
                              void* d_out, int out_size, void* d_ws, size_t ws_size,
                              hipStream_t stream) {
    const float* x  = (const float*)d_in[0];
    const float* wq = (const float*)d_in[1];
    const float* bq = (const float*)d_in[2];
    const float* wk = (const float*)d_in[3];
    const float* bk = (const float*)d_in[4];
    const float* wv = (const float*)d_in[5];
    const float* bv = (const float*)d_in[6];
    float* out = (float*)d_out;

    dim3 grid(16 * 1024);   // one wave per (b,h)
    dim3 block(64);
    fused_attn_c4_f32<<<grid, block, 0, stream>>>(x, wq, bq, wk, bk, wv, bv, out);
}